// Round 15
// baseline (1266.351 us; speedup 1.0000x reference)
//
#include <hip/hip_runtime.h>
#include <hip/hip_bf16.h>
#include <math.h>

#define NN 8192
#define DD 256
#define HH 128
#define RPB 16
#define DT_F 0.01f
#define TWO_PI_F 6.28318530717958647692f
#define ROWB 9216   // packed bytes per row: 8192 low-byte + 1024 hi-1bit

__device__ __forceinline__ float gelu_exact(float t) {
    return 0.5f * t * (1.f + erff(t * 0.70710678118654752440f));
}
__device__ __forceinline__ float sigmoidf(float t) {
    return 1.f / (1.f + expf(-t));
}

// 9-bit unpack + accumulate: 4 elements of one lo-word (r14 verified).
__device__ __forceinline__ void acc9(unsigned lo, unsigned w,
                                     float4 cv, float4 sv, float& ac, float& as) {
#if __has_builtin(__builtin_amdgcn_perm)
    unsigned u0 = __builtin_amdgcn_perm(w, lo, 0x0C0C0400u);
    unsigned u1 = __builtin_amdgcn_perm(w, lo, 0x0C0C0501u);
    unsigned u2 = __builtin_amdgcn_perm(w, lo, 0x0C0C0602u);
    unsigned u3 = __builtin_amdgcn_perm(w, lo, 0x0C0C0703u);
#else
    unsigned u0 = ((lo >> 0)  & 0xFFu) | (((w >> 0)  & 0xFFu) << 8);
    unsigned u1 = ((lo >> 8)  & 0xFFu) | (((w >> 8)  & 0xFFu) << 8);
    unsigned u2 = ((lo >> 16) & 0xFFu) | (((w >> 16) & 0xFFu) << 8);
    unsigned u3 = ((lo >> 24) & 0xFFu) | (((w >> 24) & 0xFFu) << 8);
#endif
    float f0 = (float)u0, f1 = (float)u1, f2 = (float)u2, f3 = (float)u3;
    ac = fmaf(f0, cv.x, ac); as = fmaf(f0, sv.x, as);
    ac = fmaf(f1, cv.y, ac); as = fmaf(f1, sv.y, as);
    ac = fmaf(f2, cv.z, ac); as = fmaf(f2, sv.z, as);
    ac = fmaf(f3, cv.w, ac); as = fmaf(f3, sv.w, as);
}

// expand nibble j of h (4x 1-bit fields) into one 1-bit value per byte
__device__ __forceinline__ unsigned spread1(unsigned h, int j) {
    unsigned t = (h >> (4 * j)) & 0xFu;
    return (t | (t << 7) | (t << 14) | (t << 21)) & 0x01010101u;
}

// ---------------- A fp32 -> packed 9-bit (r14 layout, verbatim) -------------
__global__ __launch_bounds__(512) void convert_pack_kernel(
    const float* __restrict__ A, unsigned char* __restrict__ Ap)
{
    const int row = blockIdx.x;
    const int g = threadIdx.x;
    const int lane = g & 63, itq = g >> 6;
    const float* src = A + (size_t)row * NN + 4 * lane + 1024 * itq;
    unsigned q[16];
#pragma unroll
    for (int j = 0; j < 4; ++j) {
        float4 f = *(const float4*)(src + 256 * j);
        float v[4] = {f.x, f.y, f.z, f.w};
#pragma unroll
        for (int m = 0; m < 4; ++m) {
            float c = fminf(fmaxf(v[m], 0.f), 1.f);
            q[4 * j + m] = (unsigned)__float2int_rn(c * 511.f);
        }
    }
    uint4 lo;
    lo.x = (q[0] & 0xFF) | ((q[1] & 0xFF) << 8) | ((q[2] & 0xFF) << 16) | ((q[3] & 0xFF) << 24);
    lo.y = (q[4] & 0xFF) | ((q[5] & 0xFF) << 8) | ((q[6] & 0xFF) << 16) | ((q[7] & 0xFF) << 24);
    lo.z = (q[8] & 0xFF) | ((q[9] & 0xFF) << 8) | ((q[10] & 0xFF) << 16) | ((q[11] & 0xFF) << 24);
    lo.w = (q[12] & 0xFF) | ((q[13] & 0xFF) << 8) | ((q[14] & 0xFF) << 16) | ((q[15] & 0xFF) << 24);
    unsigned hi = 0;
#pragma unroll
    for (int b = 0; b < 16; ++b)
        hi |= (q[b] >> 8) << b;
    unsigned char* rowp = Ap + (size_t)row * ROWB;
    ((uint4*)rowp)[g] = lo;
    ((unsigned short*)(rowp + 8192))[g] = (unsigned short)hi;
}

// ---------------- pre: frequencies, coupling, phases0, cos/sin snapshot ----
__global__ __launch_bounds__(256) void pre_kernel(
    const float* __restrict__ x,
    const float* __restrict__ fw1, const float* __restrict__ fb1,
    const float* __restrict__ flng, const float* __restrict__ flnb,
    const float* __restrict__ fw2, const float* __restrict__ fb2,
    const float* __restrict__ fw3, const float* __restrict__ fb3,
    const float* __restrict__ cw1, const float* __restrict__ cb1,
    const float* __restrict__ cw2, const float* __restrict__ cb2,
    const float* __restrict__ gcp,
    float* __restrict__ freq_out, float* __restrict__ coup_out,
    float* __restrict__ cs_ws, float* __restrict__ phases_out,
    float* __restrict__ pc0f, float* __restrict__ ps0f)
{
    __shared__ float xs[RPB][DD];
    __shared__ float h1[RPB][DD];
    __shared__ float h2[RPB][HH];
    __shared__ float hc[RPB][HH];
    const int tid = threadIdx.x;
    const int base_row = blockIdx.x * RPB;

    {
        const float4* xg = (const float4*)(x + (size_t)base_row * DD);
        float4* xv = (float4*)&xs[0][0];
        for (int i = tid; i < RPB * DD / 4; i += 256) xv[i] = xg[i];
    }
    __syncthreads();

    {
        float acc[RPB];
#pragma unroll
        for (int r = 0; r < RPB; ++r) acc[r] = 0.f;
        const int c = tid;
        for (int k = 0; k < DD; k += 4) {
            float w0 = fw1[(k + 0) * DD + c];
            float w1 = fw1[(k + 1) * DD + c];
            float w2 = fw1[(k + 2) * DD + c];
            float w3 = fw1[(k + 3) * DD + c];
#pragma unroll
            for (int r = 0; r < RPB; ++r) {
                float4 xv = *(const float4*)&xs[r][k];
                acc[r] += xv.x * w0 + xv.y * w1 + xv.z * w2 + xv.w * w3;
            }
        }
        float bb = fb1[c];
#pragma unroll
        for (int r = 0; r < RPB; ++r) h1[r][c] = acc[r] + bb;
    }
    __syncthreads();

    {
        const int wave = tid >> 6, lane = tid & 63;
        for (int r = wave; r < RPB; r += 4) {
            float v0 = h1[r][lane], v1 = h1[r][lane + 64], v2 = h1[r][lane + 128], v3 = h1[r][lane + 192];
            float s = v0 + v1 + v2 + v3;
            for (int off = 32; off; off >>= 1) s += __shfl_xor(s, off);
            float m = s * (1.f / DD);
            float d0 = v0 - m, d1 = v1 - m, d2 = v2 - m, d3 = v3 - m;
            float q = d0 * d0 + d1 * d1 + d2 * d2 + d3 * d3;
            for (int off = 32; off; off >>= 1) q += __shfl_xor(q, off);
            float rstd = rsqrtf(q * (1.f / DD) + 1e-5f);
            h1[r][lane]       = tanhf(d0 * rstd * flng[lane]       + flnb[lane]);
            h1[r][lane + 64]  = tanhf(d1 * rstd * flng[lane + 64]  + flnb[lane + 64]);
            h1[r][lane + 128] = tanhf(d2 * rstd * flng[lane + 128] + flnb[lane + 128]);
            h1[r][lane + 192] = tanhf(d3 * rstd * flng[lane + 192] + flnb[lane + 192]);
        }
    }
    __syncthreads();

    if (tid < HH) {
        const int c = tid;
        float acc[RPB];
#pragma unroll
        for (int r = 0; r < RPB; ++r) acc[r] = 0.f;
        for (int k = 0; k < DD; k += 4) {
            float w0 = fw2[(k + 0) * HH + c];
            float w1 = fw2[(k + 1) * HH + c];
            float w2 = fw2[(k + 2) * HH + c];
            float w3 = fw2[(k + 3) * HH + c];
#pragma unroll
            for (int r = 0; r < RPB; ++r) {
                float4 xv = *(const float4*)&h1[r][k];
                acc[r] += xv.x * w0 + xv.y * w1 + xv.z * w2 + xv.w * w3;
            }
        }
        float bb = fb2[c];
#pragma unroll
        for (int r = 0; r < RPB; ++r) h2[r][c] = tanhf(acc[r] + bb);
    } else {
        const int c = tid - HH;
        float acc[RPB];
#pragma unroll
        for (int r = 0; r < RPB; ++r) acc[r] = 0.f;
        for (int k = 0; k < DD; k += 4) {
            float w0 = cw1[(k + 0) * HH + c];
            float w1 = cw1[(k + 1) * HH + c];
            float w2 = cw1[(k + 2) * HH + c];
            float w3 = cw1[(k + 3) * HH + c];
#pragma unroll
            for (int r = 0; r < RPB; ++r) {
                float4 xv = *(const float4*)&xs[r][k];
                acc[r] += xv.x * w0 + xv.y * w1 + xv.z * w2 + xv.w * w3;
            }
        }
        float bb = cb1[c];
#pragma unroll
        for (int r = 0; r < RPB; ++r) {
            float t = acc[r] + bb;
            hc[r][c] = gelu_exact(t);
        }
    }
    __syncthreads();

    {
        const int wave = tid >> 6, lane = tid & 63;
        float gc = fminf(fmaxf(gcp[0], 0.1f), 2.0f);
        for (int r = wave; r < RPB; r += 4) {
            float f = h2[r][lane] * fw3[lane] + h2[r][lane + 64] * fw3[lane + 64];
            for (int off = 32; off; off >>= 1) f += __shfl_xor(f, off);
            float cpl = hc[r][lane] * cw2[lane] + hc[r][lane + 64] * cw2[lane + 64];
            for (int off = 32; off; off >>= 1) cpl += __shfl_xor(cpl, off);
            float ssum = 0.f, csum = 0.f;
#pragma unroll
            for (int j = 0; j < 4; ++j) {
                int idx = lane + 64 * j;
                float xv = xs[r][idx];
                float fi = (float)idx;
                ssum += xv * sinf(fi);
                csum += xv * cosf(fi);
            }
            for (int off = 32; off; off >>= 1) {
                ssum += __shfl_xor(ssum, off);
                csum += __shfl_xor(csum, off);
            }
            if (lane == 0) {
                int row = base_row + r;
                freq_out[row] = f + fb3[0];
                float sg = sigmoidf(cpl + cb2[0]);
                coup_out[row] = sg;
                cs_ws[row] = sg * gc;
                float ph = atan2f(ssum, csum);
                phases_out[row] = ph;
                pc0f[row] = cosf(ph);
                ps0f[row] = sinf(ph);
            }
        }
    }
}

// ---------------- group body: 16 cols x 2 rows, f32 global vectors ----------
__device__ __forceinline__ void group_body(
    uint4 lo0, uint4 lo1, unsigned h0, unsigned h1,
    const float4* __restrict__ Pc, const float4* __restrict__ Ps, int base,
    float& lac0, float& las0, float& lac1, float& las1)
{
    float4 c0 = Pc[base], c1 = Pc[base + 64], c2 = Pc[base + 128], c3 = Pc[base + 192];
    float4 s0 = Ps[base], s1 = Ps[base + 64], s2 = Ps[base + 128], s3 = Ps[base + 192];
    acc9(lo0.x, spread1(h0, 0), c0, s0, lac0, las0);
    acc9(lo1.x, spread1(h1, 0), c0, s0, lac1, las1);
    acc9(lo0.y, spread1(h0, 1), c1, s1, lac0, las0);
    acc9(lo1.y, spread1(h1, 1), c1, s1, lac1, las1);
    acc9(lo0.z, spread1(h0, 2), c2, s2, lac0, las0);
    acc9(lo1.z, spread1(h1, 2), c2, s2, lac1, las1);
    acc9(lo0.w, spread1(h0, 3), c3, s3, lac0, las0);
    acc9(lo1.w, spread1(h1, 3), c3, s3, lac1, las1);
}

// ---------------- one Kuramoto step (9-bit A, f32 vectors from L2) ----------
// No LDS staging: the 64 KB cos/sin planes are L2-resident; every block reads
// them directly with the same coalesced float4 pattern. No staging barrier.
#define SROWS 16   // 8 waves x 2 rows
__global__ __launch_bounds__(512) void step_kernel_p(
    const unsigned char* __restrict__ Ap,
    const float* __restrict__ vcin, const float* __restrict__ vsin,
    const float* __restrict__ freq, const float* __restrict__ cs,
    float* __restrict__ phases,
    float* __restrict__ vcout, float* __restrict__ vsout)
{
    __shared__ float part[8][4];
    const int tid = threadIdx.x, l = tid & 63, w = tid >> 6;

    const int row0 = blockIdx.x * SROWS + w * 2;
    const uint4* lo0p = (const uint4*)(Ap + (size_t)(row0 + 0) * ROWB);
    const uint4* lo1p = (const uint4*)(Ap + (size_t)(row0 + 1) * ROWB);
    const unsigned short* h0p = (const unsigned short*)(Ap + (size_t)(row0 + 0) * ROWB + 8192);
    const unsigned short* h1p = (const unsigned short*)(Ap + (size_t)(row0 + 1) * ROWB + 8192);
    const float4* Pc = (const float4*)vcin;
    const float4* Ps = (const float4*)vsin;

    float lac0 = 0.f, las0 = 0.f, lac1 = 0.f, las1 = 0.f;
#pragma unroll 2
    for (int it = 0; it < 8; ++it) {
        const int g = it * 64 + l;
        uint4 lo0 = lo0p[g];
        uint4 lo1 = lo1p[g];
        unsigned h0 = h0p[g];
        unsigned h1 = h1p[g];
        group_body(lo0, lo1, h0, h1, Pc, Ps, l + 256 * it, lac0, las0, lac1, las1);
    }
    for (int off = 32; off; off >>= 1) {
        lac0 += __shfl_xor(lac0, off);
        las0 += __shfl_xor(las0, off);
        lac1 += __shfl_xor(lac1, off);
        las1 += __shfl_xor(las1, off);
    }
    if (l == 0) {
        part[w][0] = lac0; part[w][1] = las0;
        part[w][2] = lac1; part[w][3] = las1;
    }
    __syncthreads();
    if (tid < SROWS) {
        const int R = blockIdx.x * SROWS + tid;
        const float inv = 1.f / 511.f;
        float c = part[tid >> 1][2 * (tid & 1)] * inv;
        float s = part[tid >> 1][2 * (tid & 1) + 1] * inv;
        float ph = phases[R];
        float ce = atan2f(s, c + 1e-8f) - ph;
        float dphi = freq[R] + cs[R] * sinf(ce);
        float pn = fmodf(ph + DT_F * dphi, TWO_PI_F);
        if (pn < 0.f) pn += TWO_PI_F;
        phases[R] = pn;
        vcout[R] = cosf(pn);
        vsout[R] = sinf(pn);
    }
}

// ---------------- fp32 fallback step (ws too small) -------------------------
#define FSROWS 8
#define CHUNK 4096
__global__ __launch_bounds__(256) void step_kernel(
    const float* __restrict__ A,
    const float* __restrict__ pc_in, const float* __restrict__ ps_in,
    const float* __restrict__ freq, const float* __restrict__ cs,
    float* __restrict__ phases,
    float* __restrict__ pc_out, float* __restrict__ ps_out)
{
    __shared__ float pcs[CHUNK];
    __shared__ float pss[CHUNK];
    const int tid = threadIdx.x, lane = tid & 63, wave = tid >> 6;
    const int row0 = blockIdx.x * FSROWS + wave * (FSROWS / 4);
    float accC[FSROWS / 4], accS[FSROWS / 4];
#pragma unroll
    for (int rr = 0; rr < FSROWS / 4; ++rr) { accC[rr] = 0.f; accS[rr] = 0.f; }
    for (int ch = 0; ch < NN / CHUNK; ++ch) {
        const float4* pcg = (const float4*)(pc_in + ch * CHUNK);
        const float4* psg = (const float4*)(ps_in + ch * CHUNK);
        for (int i = tid; i < CHUNK / 4; i += 256) {
            ((float4*)pcs)[i] = pcg[i];
            ((float4*)pss)[i] = psg[i];
        }
        __syncthreads();
#pragma unroll
        for (int rr = 0; rr < FSROWS / 4; ++rr) {
            const float4* Ar = (const float4*)(A + (size_t)(row0 + rr) * NN + ch * CHUNK);
            float lac = 0.f, las = 0.f;
#pragma unroll 4
            for (int it = 0; it < CHUNK / 256; ++it) {
                int c4 = it * 64 + lane;
                float4 a = Ar[c4];
                float4 c = ((const float4*)pcs)[c4];
                float4 s = ((const float4*)pss)[c4];
                lac += a.x * c.x + a.y * c.y + a.z * c.z + a.w * c.w;
                las += a.x * s.x + a.y * s.y + a.z * s.z + a.w * s.w;
            }
            accC[rr] += lac;
            accS[rr] += las;
        }
        __syncthreads();
    }
#pragma unroll
    for (int rr = 0; rr < FSROWS / 4; ++rr) {
        float c = accC[rr], s = accS[rr];
        for (int off = 32; off; off >>= 1) {
            c += __shfl_xor(c, off);
            s += __shfl_xor(s, off);
        }
        if (lane == 0) {
            int row = row0 + rr;
            float ph = phases[row];
            float ce = atan2f(s, c + 1e-8f) - ph;
            float dphi = freq[row] + cs[row] * sinf(ce);
            float pn = fmodf(ph + DT_F * dphi, TWO_PI_F);
            if (pn < 0.f) pn += TWO_PI_F;
            phases[row] = pn;
            pc_out[row] = cosf(pn);
            ps_out[row] = sinf(pn);
        }
    }
}

// ---------------- post: sync_input, sync MLP -> desync ----------------------
#define SD 260
#define SDP 264
__global__ __launch_bounds__(256) void post_kernel(
    const float* __restrict__ x, const float* __restrict__ phases,
    const float* __restrict__ sw1, const float* __restrict__ sb1,
    const float* __restrict__ slng, const float* __restrict__ slnb,
    const float* __restrict__ sw2, const float* __restrict__ sb2,
    const float* __restrict__ sw3, const float* __restrict__ sb3,
    float* __restrict__ sync_out, float* __restrict__ desync_out)
{
    __shared__ float xs[RPB][SDP];
    __shared__ float h1[RPB][DD];
    __shared__ float h2[RPB][HH];
    const int tid = threadIdx.x;
    const int base_row = blockIdx.x * RPB;

    for (int i = tid; i < RPB * DD / 4; i += 256) {
        int r = i / (DD / 4), c4 = i % (DD / 4);
        *(float4*)&xs[r][c4 * 4] = ((const float4*)(x + (size_t)(base_row + r) * DD))[c4];
    }
    if (tid < RPB) {
        float p = phases[base_row + tid];
        xs[tid][256] = cosf(p);
        xs[tid][257] = sinf(p);
        xs[tid][258] = cosf(2.f * p);
        xs[tid][259] = sinf(2.f * p);
    }
    __syncthreads();

    for (int i = tid; i < RPB * SD; i += 256) {
        int r = i / SD, c = i % SD;
        sync_out[(size_t)(base_row + r) * SD + c] = xs[r][c];
    }

    {
        float acc[RPB];
#pragma unroll
        for (int r = 0; r < RPB; ++r) acc[r] = 0.f;
        const int c = tid;
        for (int k = 0; k < SD; k += 4) {
            float w0 = sw1[(k + 0) * DD + c];
            float w1 = sw1[(k + 1) * DD + c];
            float w2 = sw1[(k + 2) * DD + c];
            float w3 = sw1[(k + 3) * DD + c];
#pragma unroll
            for (int r = 0; r < RPB; ++r) {
                float4 xv = *(const float4*)&xs[r][k];
                acc[r] += xv.x * w0 + xv.y * w1 + xv.z * w2 + xv.w * w3;
            }
        }
        float bb = sb1[c];
#pragma unroll
        for (int r = 0; r < RPB; ++r) h1[r][c] = acc[r] + bb;
    }
    __syncthreads();

    {
        const int wave = tid >> 6, lane = tid & 63;
        for (int r = wave; r < RPB; r += 4) {
            float v0 = h1[r][lane], v1 = h1[r][lane + 64], v2 = h1[r][lane + 128], v3 = h1[r][lane + 192];
            float s = v0 + v1 + v2 + v3;
            for (int off = 32; off; off >>= 1) s += __shfl_xor(s, off);
            float m = s * (1.f / DD);
            float d0 = v0 - m, d1 = v1 - m, d2 = v2 - m, d3 = v3 - m;
            float q = d0 * d0 + d1 * d1 + d2 * d2 + d3 * d3;
            for (int off = 32; off; off >>= 1) q += __shfl_xor(q, off);
            float rstd = rsqrtf(q * (1.f / DD) + 1e-5f);
            h1[r][lane]       = gelu_exact(d0 * rstd * slng[lane]       + slnb[lane]);
            h1[r][lane + 64]  = gelu_exact(d1 * rstd * slng[lane + 64]  + slnb[lane + 64]);
            h1[r][lane + 128] = gelu_exact(d2 * rstd * slng[lane + 128] + slnb[lane + 128]);
            h1[r][lane + 192] = gelu_exact(d3 * rstd * slng[lane + 192] + slnb[lane + 192]);
        }
    }
    __syncthreads();

    if (tid < HH) {
        const int c = tid;
        float acc[RPB];
#pragma unroll
        for (int r = 0; r < RPB; ++r) acc[r] = 0.f;
        for (int k = 0; k < DD; k += 4) {
            float w0 = sw2[(k + 0) * HH + c];
            float w1 = sw2[(k + 1) * HH + c];
            float w2 = sw2[(k + 2) * HH + c];
            float w3 = sw2[(k + 3) * HH + c];
#pragma unroll
            for (int r = 0; r < RPB; ++r) {
                float4 xv = *(const float4*)&h1[r][k];
                acc[r] += xv.x * w0 + xv.y * w1 + xv.z * w2 + xv.w * w3;
            }
        }
        float bb = sb2[c];
#pragma unroll
        for (int r = 0; r < RPB; ++r) h2[r][c] = gelu_exact(acc[r] + bb);
    }
    __syncthreads();

    {
        const int wave = tid >> 6, lane = tid & 63;
        for (int r = wave; r < RPB; r += 4) {
            float t = h2[r][lane] * sw3[lane] + h2[r][lane + 64] * sw3[lane + 64];
            for (int off = 32; off; off >>= 1) t += __shfl_xor(t, off);
            if (lane == 0) desync_out[base_row + r] = sigmoidf(t + sb3[0]);
        }
    }
}

// ---------------- global scalar reductions ---------------------------------
__global__ __launch_bounds__(1024) void reduce_kernel(
    const float* __restrict__ phases,
    float* __restrict__ order_out, float* __restrict__ coh_out)
{
    __shared__ double red[16][4];
    const int tid = threadIdx.x;
    double sc = 0, ss = 0, sp = 0, spp = 0;
    for (int i = tid; i < NN; i += 1024) {
        float p = phases[i];
        sc += (double)cosf(p);
        ss += (double)sinf(p);
        sp += (double)p;
        spp += (double)p * (double)p;
    }
    const int lane = tid & 63, wave = tid >> 6;
    for (int off = 32; off; off >>= 1) {
        sc += __shfl_xor(sc, off);
        ss += __shfl_xor(ss, off);
        sp += __shfl_xor(sp, off);
        spp += __shfl_xor(spp, off);
    }
    if (lane == 0) { red[wave][0] = sc; red[wave][1] = ss; red[wave][2] = sp; red[wave][3] = spp; }
    __syncthreads();
    if (tid == 0) {
        sc = 0; ss = 0; sp = 0; spp = 0;
        for (int w = 0; w < 16; ++w) { sc += red[w][0]; ss += red[w][1]; sp += red[w][2]; spp += red[w][3]; }
        double mc = sc / NN, ms = ss / NN;
        order_out[0] = (float)sqrt(mc * mc + ms * ms);
        double var = (spp - sp * sp / NN) / (NN - 1);
        if (var < 0) var = 0;
        coh_out[0] = (float)(1.0 / (1.0 + sqrt(var)));
    }
}

extern "C" void kernel_launch(void* const* d_in, const int* in_sizes, int n_in,
                              void* d_out, int out_size, void* d_ws, size_t ws_size,
                              hipStream_t stream) {
    const float* x    = (const float*)d_in[0];
    const float* A    = (const float*)d_in[1];
    const float* fw1  = (const float*)d_in[2];
    const float* fb1  = (const float*)d_in[3];
    const float* flng = (const float*)d_in[4];
    const float* flnb = (const float*)d_in[5];
    const float* fw2  = (const float*)d_in[6];
    const float* fb2  = (const float*)d_in[7];
    const float* fw3  = (const float*)d_in[8];
    const float* fb3  = (const float*)d_in[9];
    const float* cw1  = (const float*)d_in[10];
    const float* cb1  = (const float*)d_in[11];
    const float* cw2  = (const float*)d_in[12];
    const float* cb2  = (const float*)d_in[13];
    const float* sw1  = (const float*)d_in[14];
    const float* sb1  = (const float*)d_in[15];
    const float* slng = (const float*)d_in[16];
    const float* slnb = (const float*)d_in[17];
    const float* sw2  = (const float*)d_in[18];
    const float* sb2  = (const float*)d_in[19];
    const float* sw3  = (const float*)d_in[20];
    const float* sb3  = (const float*)d_in[21];
    const float* gcp  = (const float*)d_in[22];

    float* out    = (float*)d_out;
    float* desync = out;                    // 8192
    float* order  = out + 8192;             // 1
    float* phases = out + 8193;             // 8192
    float* freqo  = out + 16385;            // 8192
    float* coupo  = out + 24577;            // 8192
    float* synco  = out + 32769;            // 8192*260
    float* coh    = out + 2162689;          // 1

    char* wsb = (char*)d_ws;
    float* cs   = (float*)(wsb + 0);         // 32 KB
    float* pcA  = (float*)(wsb + 32768);     // 32 KB each, f32 planes
    float* psA  = (float*)(wsb + 65536);
    float* pcB  = (float*)(wsb + 98304);
    float* psB  = (float*)(wsb + 131072);
    unsigned char* Ap = (unsigned char*)(wsb + 262144);  // 72 MiB packed A

    const bool usepack = ws_size >= (size_t)262144 + (size_t)NN * ROWB;

    if (usepack) {
        convert_pack_kernel<<<NN, 512, 0, stream>>>(A, Ap);
    }
    pre_kernel<<<NN / RPB, 256, 0, stream>>>(x, fw1, fb1, flng, flnb, fw2, fb2, fw3, fb3,
                                             cw1, cb1, cw2, cb2, gcp,
                                             freqo, coupo, cs, phases, pcA, psA);
    if (usepack) {
        for (int t = 0; t < 60; ++t) {
            const float* vci = (t & 1) ? pcB : pcA;
            const float* vsi = (t & 1) ? psB : psA;
            float* vco = (t & 1) ? pcA : pcB;
            float* vso = (t & 1) ? psA : psB;
            step_kernel_p<<<NN / SROWS, 512, 0, stream>>>(Ap, vci, vsi, freqo, cs, phases, vco, vso);
        }
    } else {
        for (int t = 0; t < 60; ++t) {
            const float* pin  = (t & 1) ? pcB : pcA;
            const float* sin_ = (t & 1) ? psB : psA;
            float* pout = (t & 1) ? pcA : pcB;
            float* sout = (t & 1) ? psA : psB;
            step_kernel<<<NN / FSROWS, 256, 0, stream>>>(A, pin, sin_, freqo, cs, phases, pout, sout);
        }
    }
    post_kernel<<<NN / RPB, 256, 0, stream>>>(x, phases, sw1, sb1, slng, slnb, sw2, sb2, sw3, sb3,
                                              synco, desync);
    reduce_kernel<<<1, 1024, 0, stream>>>(phases, order, coh);
}

// Round 16
// 1108.861 us; speedup vs baseline: 1.1420x; 1.1420x over previous
//
#include <hip/hip_runtime.h>
#include <hip/hip_bf16.h>
#include <hip/hip_fp16.h>
#include <math.h>

#define NN 8192
#define DD 256
#define HH 128
#define RPB 16
#define DT_F 0.01f
#define TWO_PI_F 6.28318530717958647692f
#define ROWB 9216   // packed bytes per row: 8192 low-byte + 1024 hi-1bit

__device__ __forceinline__ float gelu_exact(float t) {
    return 0.5f * t * (1.f + erff(t * 0.70710678118654752440f));
}
__device__ __forceinline__ float sigmoidf(float t) {
    return 1.f / (1.f + expf(-t));
}

// 9-bit unpack + accumulate: 4 elements of one lo-word (r14 verified).
__device__ __forceinline__ void acc9(unsigned lo, unsigned w,
                                     float4 cv, float4 sv, float& ac, float& as) {
#if __has_builtin(__builtin_amdgcn_perm)
    unsigned u0 = __builtin_amdgcn_perm(w, lo, 0x0C0C0400u);
    unsigned u1 = __builtin_amdgcn_perm(w, lo, 0x0C0C0501u);
    unsigned u2 = __builtin_amdgcn_perm(w, lo, 0x0C0C0602u);
    unsigned u3 = __builtin_amdgcn_perm(w, lo, 0x0C0C0703u);
#else
    unsigned u0 = ((lo >> 0)  & 0xFFu) | (((w >> 0)  & 0xFFu) << 8);
    unsigned u1 = ((lo >> 8)  & 0xFFu) | (((w >> 8)  & 0xFFu) << 8);
    unsigned u2 = ((lo >> 16) & 0xFFu) | (((w >> 16) & 0xFFu) << 8);
    unsigned u3 = ((lo >> 24) & 0xFFu) | (((w >> 24) & 0xFFu) << 8);
#endif
    float f0 = (float)u0, f1 = (float)u1, f2 = (float)u2, f3 = (float)u3;
    ac = fmaf(f0, cv.x, ac); as = fmaf(f0, sv.x, as);
    ac = fmaf(f1, cv.y, ac); as = fmaf(f1, sv.y, as);
    ac = fmaf(f2, cv.z, ac); as = fmaf(f2, sv.z, as);
    ac = fmaf(f3, cv.w, ac); as = fmaf(f3, sv.w, as);
}

// expand nibble j of h (4x 1-bit fields) into one 1-bit value per byte
__device__ __forceinline__ unsigned spread1(unsigned h, int j) {
    unsigned t = (h >> (4 * j)) & 0xFu;
    return (t | (t << 7) | (t << 14) | (t << 21)) & 0x01010101u;
}

// ---------------- A fp32 -> packed 9-bit (r14 layout, verbatim) -------------
__global__ __launch_bounds__(512) void convert_pack_kernel(
    const float* __restrict__ A, unsigned char* __restrict__ Ap)
{
    const int row = blockIdx.x;
    const int g = threadIdx.x;
    const int lane = g & 63, itq = g >> 6;
    const float* src = A + (size_t)row * NN + 4 * lane + 1024 * itq;
    unsigned q[16];
#pragma unroll
    for (int j = 0; j < 4; ++j) {
        float4 f = *(const float4*)(src + 256 * j);
        float v[4] = {f.x, f.y, f.z, f.w};
#pragma unroll
        for (int m = 0; m < 4; ++m) {
            float c = fminf(fmaxf(v[m], 0.f), 1.f);
            q[4 * j + m] = (unsigned)__float2int_rn(c * 511.f);
        }
    }
    uint4 lo;
    lo.x = (q[0] & 0xFF) | ((q[1] & 0xFF) << 8) | ((q[2] & 0xFF) << 16) | ((q[3] & 0xFF) << 24);
    lo.y = (q[4] & 0xFF) | ((q[5] & 0xFF) << 8) | ((q[6] & 0xFF) << 16) | ((q[7] & 0xFF) << 24);
    lo.z = (q[8] & 0xFF) | ((q[9] & 0xFF) << 8) | ((q[10] & 0xFF) << 16) | ((q[11] & 0xFF) << 24);
    lo.w = (q[12] & 0xFF) | ((q[13] & 0xFF) << 8) | ((q[14] & 0xFF) << 16) | ((q[15] & 0xFF) << 24);
    unsigned hi = 0;
#pragma unroll
    for (int b = 0; b < 16; ++b)
        hi |= (q[b] >> 8) << b;
    unsigned char* rowp = Ap + (size_t)row * ROWB;
    ((uint4*)rowp)[g] = lo;
    ((unsigned short*)(rowp + 8192))[g] = (unsigned short)hi;
}

// ---------------- pre: frequencies, coupling, phases0, cos/sin snapshot ----
__global__ __launch_bounds__(256) void pre_kernel(
    const float* __restrict__ x,
    const float* __restrict__ fw1, const float* __restrict__ fb1,
    const float* __restrict__ flng, const float* __restrict__ flnb,
    const float* __restrict__ fw2, const float* __restrict__ fb2,
    const float* __restrict__ fw3, const float* __restrict__ fb3,
    const float* __restrict__ cw1, const float* __restrict__ cb1,
    const float* __restrict__ cw2, const float* __restrict__ cb2,
    const float* __restrict__ gcp,
    float* __restrict__ freq_out, float* __restrict__ coup_out,
    float* __restrict__ cs_ws, float* __restrict__ phases_out,
    float* __restrict__ pc0f, float* __restrict__ ps0f,
    unsigned* __restrict__ v0u)   // interleaved half2 {cos,sin} per row
{
    __shared__ float xs[RPB][DD];
    __shared__ float h1[RPB][DD];
    __shared__ float h2[RPB][HH];
    __shared__ float hc[RPB][HH];
    const int tid = threadIdx.x;
    const int base_row = blockIdx.x * RPB;

    {
        const float4* xg = (const float4*)(x + (size_t)base_row * DD);
        float4* xv = (float4*)&xs[0][0];
        for (int i = tid; i < RPB * DD / 4; i += 256) xv[i] = xg[i];
    }
    __syncthreads();

    {
        float acc[RPB];
#pragma unroll
        for (int r = 0; r < RPB; ++r) acc[r] = 0.f;
        const int c = tid;
        for (int k = 0; k < DD; k += 4) {
            float w0 = fw1[(k + 0) * DD + c];
            float w1 = fw1[(k + 1) * DD + c];
            float w2 = fw1[(k + 2) * DD + c];
            float w3 = fw1[(k + 3) * DD + c];
#pragma unroll
            for (int r = 0; r < RPB; ++r) {
                float4 xv = *(const float4*)&xs[r][k];
                acc[r] += xv.x * w0 + xv.y * w1 + xv.z * w2 + xv.w * w3;
            }
        }
        float bb = fb1[c];
#pragma unroll
        for (int r = 0; r < RPB; ++r) h1[r][c] = acc[r] + bb;
    }
    __syncthreads();

    {
        const int wave = tid >> 6, lane = tid & 63;
        for (int r = wave; r < RPB; r += 4) {
            float v0 = h1[r][lane], v1 = h1[r][lane + 64], v2 = h1[r][lane + 128], v3 = h1[r][lane + 192];
            float s = v0 + v1 + v2 + v3;
            for (int off = 32; off; off >>= 1) s += __shfl_xor(s, off);
            float m = s * (1.f / DD);
            float d0 = v0 - m, d1 = v1 - m, d2 = v2 - m, d3 = v3 - m;
            float q = d0 * d0 + d1 * d1 + d2 * d2 + d3 * d3;
            for (int off = 32; off; off >>= 1) q += __shfl_xor(q, off);
            float rstd = rsqrtf(q * (1.f / DD) + 1e-5f);
            h1[r][lane]       = tanhf(d0 * rstd * flng[lane]       + flnb[lane]);
            h1[r][lane + 64]  = tanhf(d1 * rstd * flng[lane + 64]  + flnb[lane + 64]);
            h1[r][lane + 128] = tanhf(d2 * rstd * flng[lane + 128] + flnb[lane + 128]);
            h1[r][lane + 192] = tanhf(d3 * rstd * flng[lane + 192] + flnb[lane + 192]);
        }
    }
    __syncthreads();

    if (tid < HH) {
        const int c = tid;
        float acc[RPB];
#pragma unroll
        for (int r = 0; r < RPB; ++r) acc[r] = 0.f;
        for (int k = 0; k < DD; k += 4) {
            float w0 = fw2[(k + 0) * HH + c];
            float w1 = fw2[(k + 1) * HH + c];
            float w2 = fw2[(k + 2) * HH + c];
            float w3 = fw2[(k + 3) * HH + c];
#pragma unroll
            for (int r = 0; r < RPB; ++r) {
                float4 xv = *(const float4*)&h1[r][k];
                acc[r] += xv.x * w0 + xv.y * w1 + xv.z * w2 + xv.w * w3;
            }
        }
        float bb = fb2[c];
#pragma unroll
        for (int r = 0; r < RPB; ++r) h2[r][c] = tanhf(acc[r] + bb);
    } else {
        const int c = tid - HH;
        float acc[RPB];
#pragma unroll
        for (int r = 0; r < RPB; ++r) acc[r] = 0.f;
        for (int k = 0; k < DD; k += 4) {
            float w0 = cw1[(k + 0) * HH + c];
            float w1 = cw1[(k + 1) * HH + c];
            float w2 = cw1[(k + 2) * HH + c];
            float w3 = cw1[(k + 3) * HH + c];
#pragma unroll
            for (int r = 0; r < RPB; ++r) {
                float4 xv = *(const float4*)&xs[r][k];
                acc[r] += xv.x * w0 + xv.y * w1 + xv.z * w2 + xv.w * w3;
            }
        }
        float bb = cb1[c];
#pragma unroll
        for (int r = 0; r < RPB; ++r) {
            float t = acc[r] + bb;
            hc[r][c] = gelu_exact(t);
        }
    }
    __syncthreads();

    {
        const int wave = tid >> 6, lane = tid & 63;
        float gc = fminf(fmaxf(gcp[0], 0.1f), 2.0f);
        for (int r = wave; r < RPB; r += 4) {
            float f = h2[r][lane] * fw3[lane] + h2[r][lane + 64] * fw3[lane + 64];
            for (int off = 32; off; off >>= 1) f += __shfl_xor(f, off);
            float cpl = hc[r][lane] * cw2[lane] + hc[r][lane + 64] * cw2[lane + 64];
            for (int off = 32; off; off >>= 1) cpl += __shfl_xor(cpl, off);
            float ssum = 0.f, csum = 0.f;
#pragma unroll
            for (int j = 0; j < 4; ++j) {
                int idx = lane + 64 * j;
                float xv = xs[r][idx];
                float fi = (float)idx;
                ssum += xv * sinf(fi);
                csum += xv * cosf(fi);
            }
            for (int off = 32; off; off >>= 1) {
                ssum += __shfl_xor(ssum, off);
                csum += __shfl_xor(csum, off);
            }
            if (lane == 0) {
                int row = base_row + r;
                freq_out[row] = f + fb3[0];
                float sg = sigmoidf(cpl + cb2[0]);
                coup_out[row] = sg;
                cs_ws[row] = sg * gc;
                float ph = atan2f(ssum, csum);
                phases_out[row] = ph;
                float cph = cosf(ph), sph = sinf(ph);
                pc0f[row] = cph;
                ps0f[row] = sph;
                __half2 hv;
                hv.x = __float2half_rn(cph);
                hv.y = __float2half_rn(sph);
                v0u[row] = *(unsigned*)&hv;
            }
        }
    }
}

// ---------------- group body: 16 cols x 2 rows, f32 LDS vectors -------------
__device__ __forceinline__ void group_body(
    uint4 lo0, uint4 lo1, unsigned h0, unsigned h1,
    const float4* Pc, const float4* Ps, int base,
    float& lac0, float& las0, float& lac1, float& las1)
{
    float4 c0 = Pc[base], c1 = Pc[base + 64], c2 = Pc[base + 128], c3 = Pc[base + 192];
    float4 s0 = Ps[base], s1 = Ps[base + 64], s2 = Ps[base + 128], s3 = Ps[base + 192];
    acc9(lo0.x, spread1(h0, 0), c0, s0, lac0, las0);
    acc9(lo1.x, spread1(h1, 0), c0, s0, lac1, las1);
    acc9(lo0.y, spread1(h0, 1), c1, s1, lac0, las0);
    acc9(lo1.y, spread1(h1, 1), c1, s1, lac1, las1);
    acc9(lo0.z, spread1(h0, 2), c2, s2, lac0, las0);
    acc9(lo1.z, spread1(h1, 2), c2, s2, lac1, las1);
    acc9(lo0.w, spread1(h0, 3), c3, s3, lac0, las0);
    acc9(lo1.w, spread1(h1, 3), c3, s3, lac1, las1);
}

// ---------------- one Kuramoto step (9-bit A, f32 LDS, 512 thr) -------------
#define SROWS 16   // 8 waves x 2 rows
__global__ __launch_bounds__(512) void step_kernel_p(
    const unsigned char* __restrict__ Ap,
    const unsigned* __restrict__ vin,    // interleaved half2 {cos,sin} per row
    const float* __restrict__ freq, const float* __restrict__ cs,
    float* __restrict__ phases,
    unsigned* __restrict__ vout)
{
    __shared__ float vc[NN];        // 32 KB cos (f32)
    __shared__ float vs[NN];        // 32 KB sin (f32)
    __shared__ float part[8][4];
    const int tid = threadIdx.x, l = tid & 63, w = tid >> 6;

    const int row0 = blockIdx.x * SROWS + w * 2;
    const uint4* lo0p = (const uint4*)(Ap + (size_t)(row0 + 0) * ROWB);
    const uint4* lo1p = (const uint4*)(Ap + (size_t)(row0 + 1) * ROWB);
    const unsigned short* h0p = (const unsigned short*)(Ap + (size_t)(row0 + 0) * ROWB + 8192);
    const unsigned short* h1p = (const unsigned short*)(Ap + (size_t)(row0 + 1) * ROWB + 8192);

    // prefetch group 0 A-data (HBM latency hides under staging)
    uint4 plo0 = lo0p[l], plo1 = lo1p[l];
    unsigned ph0 = h0p[l], ph1 = h1p[l];

    // ---- stage vectors: f16 -> f32 once (exact), to LDS ----
    const unsigned long long* vin8 = (const unsigned long long*)vin;
#pragma unroll
    for (int k = 0; k < 8; ++k) {
        const int idx = tid + 512 * k;    // uint2 idx: rows 2idx, 2idx+1
        unsigned long long d = vin8[idx];
        unsigned w0 = (unsigned)d, w1 = (unsigned)(d >> 32);
        __half2 p0 = *(__half2*)&w0, p1 = *(__half2*)&w1;
        ((float2*)vc)[idx] = make_float2(__half2float(p0.x), __half2float(p1.x));
        ((float2*)vs)[idx] = make_float2(__half2float(p0.y), __half2float(p1.y));
    }
    __syncthreads();

    const float4* Pc = (const float4*)vc;
    const float4* Ps = (const float4*)vs;
    float lac0 = 0.f, las0 = 0.f, lac1 = 0.f, las1 = 0.f;

    group_body(plo0, plo1, ph0, ph1, Pc, Ps, l, lac0, las0, lac1, las1);
#pragma unroll 2
    for (int it = 1; it < 8; ++it) {
        const int g = it * 64 + l;
        uint4 lo0 = lo0p[g];
        uint4 lo1 = lo1p[g];
        unsigned h0 = h0p[g];
        unsigned h1 = h1p[g];
        group_body(lo0, lo1, h0, h1, Pc, Ps, l + 256 * it, lac0, las0, lac1, las1);
    }
    for (int off = 32; off; off >>= 1) {
        lac0 += __shfl_xor(lac0, off);
        las0 += __shfl_xor(las0, off);
        lac1 += __shfl_xor(lac1, off);
        las1 += __shfl_xor(las1, off);
    }
    if (l == 0) {
        part[w][0] = lac0; part[w][1] = las0;
        part[w][2] = lac1; part[w][3] = las1;
    }
    __syncthreads();
    if (tid < SROWS) {
        const int R = blockIdx.x * SROWS + tid;
        const float inv = 1.f / 511.f;
        float c = part[tid >> 1][2 * (tid & 1)] * inv;
        float s = part[tid >> 1][2 * (tid & 1) + 1] * inv;
        float ph = phases[R];
        float ce = atan2f(s, c + 1e-8f) - ph;
        float dphi = freq[R] + cs[R] * sinf(ce);
        float pn = fmodf(ph + DT_F * dphi, TWO_PI_F);
        if (pn < 0.f) pn += TWO_PI_F;
        phases[R] = pn;
        __half2 hv;
        hv.x = __float2half_rn(cosf(pn));
        hv.y = __float2half_rn(sinf(pn));
        vout[R] = *(unsigned*)&hv;
    }
}

// ---------------- fp32 fallback step (ws too small) -------------------------
#define FSROWS 8
#define CHUNK 4096
__global__ __launch_bounds__(256) void step_kernel(
    const float* __restrict__ A,
    const float* __restrict__ pc_in, const float* __restrict__ ps_in,
    const float* __restrict__ freq, const float* __restrict__ cs,
    float* __restrict__ phases,
    float* __restrict__ pc_out, float* __restrict__ ps_out)
{
    __shared__ float pcs[CHUNK];
    __shared__ float pss[CHUNK];
    const int tid = threadIdx.x, lane = tid & 63, wave = tid >> 6;
    const int row0 = blockIdx.x * FSROWS + wave * (FSROWS / 4);
    float accC[FSROWS / 4], accS[FSROWS / 4];
#pragma unroll
    for (int rr = 0; rr < FSROWS / 4; ++rr) { accC[rr] = 0.f; accS[rr] = 0.f; }
    for (int ch = 0; ch < NN / CHUNK; ++ch) {
        const float4* pcg = (const float4*)(pc_in + ch * CHUNK);
        const float4* psg = (const float4*)(ps_in + ch * CHUNK);
        for (int i = tid; i < CHUNK / 4; i += 256) {
            ((float4*)pcs)[i] = pcg[i];
            ((float4*)pss)[i] = psg[i];
        }
        __syncthreads();
#pragma unroll
        for (int rr = 0; rr < FSROWS / 4; ++rr) {
            const float4* Ar = (const float4*)(A + (size_t)(row0 + rr) * NN + ch * CHUNK);
            float lac = 0.f, las = 0.f;
#pragma unroll 4
            for (int it = 0; it < CHUNK / 256; ++it) {
                int c4 = it * 64 + lane;
                float4 a = Ar[c4];
                float4 c = ((const float4*)pcs)[c4];
                float4 s = ((const float4*)pss)[c4];
                lac += a.x * c.x + a.y * c.y + a.z * c.z + a.w * c.w;
                las += a.x * s.x + a.y * s.y + a.z * s.z + a.w * s.w;
            }
            accC[rr] += lac;
            accS[rr] += las;
        }
        __syncthreads();
    }
#pragma unroll
    for (int rr = 0; rr < FSROWS / 4; ++rr) {
        float c = accC[rr], s = accS[rr];
        for (int off = 32; off; off >>= 1) {
            c += __shfl_xor(c, off);
            s += __shfl_xor(s, off);
        }
        if (lane == 0) {
            int row = row0 + rr;
            float ph = phases[row];
            float ce = atan2f(s, c + 1e-8f) - ph;
            float dphi = freq[row] + cs[row] * sinf(ce);
            float pn = fmodf(ph + DT_F * dphi, TWO_PI_F);
            if (pn < 0.f) pn += TWO_PI_F;
            phases[row] = pn;
            pc_out[row] = cosf(pn);
            ps_out[row] = sinf(pn);
        }
    }
}

// ---------------- post: sync_input, sync MLP -> desync ----------------------
#define SD 260
#define SDP 264
__global__ __launch_bounds__(256) void post_kernel(
    const float* __restrict__ x, const float* __restrict__ phases,
    const float* __restrict__ sw1, const float* __restrict__ sb1,
    const float* __restrict__ slng, const float* __restrict__ slnb,
    const float* __restrict__ sw2, const float* __restrict__ sb2,
    const float* __restrict__ sw3, const float* __restrict__ sb3,
    float* __restrict__ sync_out, float* __restrict__ desync_out)
{
    __shared__ float xs[RPB][SDP];
    __shared__ float h1[RPB][DD];
    __shared__ float h2[RPB][HH];
    const int tid = threadIdx.x;
    const int base_row = blockIdx.x * RPB;

    for (int i = tid; i < RPB * DD / 4; i += 256) {
        int r = i / (DD / 4), c4 = i % (DD / 4);
        *(float4*)&xs[r][c4 * 4] = ((const float4*)(x + (size_t)(base_row + r) * DD))[c4];
    }
    if (tid < RPB) {
        float p = phases[base_row + tid];
        xs[tid][256] = cosf(p);
        xs[tid][257] = sinf(p);
        xs[tid][258] = cosf(2.f * p);
        xs[tid][259] = sinf(2.f * p);
    }
    __syncthreads();

    for (int i = tid; i < RPB * SD; i += 256) {
        int r = i / SD, c = i % SD;
        sync_out[(size_t)(base_row + r) * SD + c] = xs[r][c];
    }

    {
        float acc[RPB];
#pragma unroll
        for (int r = 0; r < RPB; ++r) acc[r] = 0.f;
        const int c = tid;
        for (int k = 0; k < SD; k += 4) {
            float w0 = sw1[(k + 0) * DD + c];
            float w1 = sw1[(k + 1) * DD + c];
            float w2 = sw1[(k + 2) * DD + c];
            float w3 = sw1[(k + 3) * DD + c];
#pragma unroll
            for (int r = 0; r < RPB; ++r) {
                float4 xv = *(const float4*)&xs[r][k];
                acc[r] += xv.x * w0 + xv.y * w1 + xv.z * w2 + xv.w * w3;
            }
        }
        float bb = sb1[c];
#pragma unroll
        for (int r = 0; r < RPB; ++r) h1[r][c] = acc[r] + bb;
    }
    __syncthreads();

    {
        const int wave = tid >> 6, lane = tid & 63;
        for (int r = wave; r < RPB; r += 4) {
            float v0 = h1[r][lane], v1 = h1[r][lane + 64], v2 = h1[r][lane + 128], v3 = h1[r][lane + 192];
            float s = v0 + v1 + v2 + v3;
            for (int off = 32; off; off >>= 1) s += __shfl_xor(s, off);
            float m = s * (1.f / DD);
            float d0 = v0 - m, d1 = v1 - m, d2 = v2 - m, d3 = v3 - m;
            float q = d0 * d0 + d1 * d1 + d2 * d2 + d3 * d3;
            for (int off = 32; off; off >>= 1) q += __shfl_xor(q, off);
            float rstd = rsqrtf(q * (1.f / DD) + 1e-5f);
            h1[r][lane]       = gelu_exact(d0 * rstd * slng[lane]       + slnb[lane]);
            h1[r][lane + 64]  = gelu_exact(d1 * rstd * slng[lane + 64]  + slnb[lane + 64]);
            h1[r][lane + 128] = gelu_exact(d2 * rstd * slng[lane + 128] + slnb[lane + 128]);
            h1[r][lane + 192] = gelu_exact(d3 * rstd * slng[lane + 192] + slnb[lane + 192]);
        }
    }
    __syncthreads();

    if (tid < HH) {
        const int c = tid;
        float acc[RPB];
#pragma unroll
        for (int r = 0; r < RPB; ++r) acc[r] = 0.f;
        for (int k = 0; k < DD; k += 4) {
            float w0 = sw2[(k + 0) * HH + c];
            float w1 = sw2[(k + 1) * HH + c];
            float w2 = sw2[(k + 2) * HH + c];
            float w3 = sw2[(k + 3) * HH + c];
#pragma unroll
            for (int r = 0; r < RPB; ++r) {
                float4 xv = *(const float4*)&h1[r][k];
                acc[r] += xv.x * w0 + xv.y * w1 + xv.z * w2 + xv.w * w3;
            }
        }
        float bb = sb2[c];
#pragma unroll
        for (int r = 0; r < RPB; ++r) h2[r][c] = gelu_exact(acc[r] + bb);
    }
    __syncthreads();

    {
        const int wave = tid >> 6, lane = tid & 63;
        for (int r = wave; r < RPB; r += 4) {
            float t = h2[r][lane] * sw3[lane] + h2[r][lane + 64] * sw3[lane + 64];
            for (int off = 32; off; off >>= 1) t += __shfl_xor(t, off);
            if (lane == 0) desync_out[base_row + r] = sigmoidf(t + sb3[0]);
        }
    }
}

// ---------------- global scalar reductions ---------------------------------
__global__ __launch_bounds__(1024) void reduce_kernel(
    const float* __restrict__ phases,
    float* __restrict__ order_out, float* __restrict__ coh_out)
{
    __shared__ double red[16][4];
    const int tid = threadIdx.x;
    double sc = 0, ss = 0, sp = 0, spp = 0;
    for (int i = tid; i < NN; i += 1024) {
        float p = phases[i];
        sc += (double)cosf(p);
        ss += (double)sinf(p);
        sp += (double)p;
        spp += (double)p * (double)p;
    }
    const int lane = tid & 63, wave = tid >> 6;
    for (int off = 32; off; off >>= 1) {
        sc += __shfl_xor(sc, off);
        ss += __shfl_xor(ss, off);
        sp += __shfl_xor(sp, off);
        spp += __shfl_xor(spp, off);
    }
    if (lane == 0) { red[wave][0] = sc; red[wave][1] = ss; red[wave][2] = sp; red[wave][3] = spp; }
    __syncthreads();
    if (tid == 0) {
        sc = 0; ss = 0; sp = 0; spp = 0;
        for (int w = 0; w < 16; ++w) { sc += red[w][0]; ss += red[w][1]; sp += red[w][2]; spp += red[w][3]; }
        double mc = sc / NN, ms = ss / NN;
        order_out[0] = (float)sqrt(mc * mc + ms * ms);
        double var = (spp - sp * sp / NN) / (NN - 1);
        if (var < 0) var = 0;
        coh_out[0] = (float)(1.0 / (1.0 + sqrt(var)));
    }
}

extern "C" void kernel_launch(void* const* d_in, const int* in_sizes, int n_in,
                              void* d_out, int out_size, void* d_ws, size_t ws_size,
                              hipStream_t stream) {
    const float* x    = (const float*)d_in[0];
    const float* A    = (const float*)d_in[1];
    const float* fw1  = (const float*)d_in[2];
    const float* fb1  = (const float*)d_in[3];
    const float* flng = (const float*)d_in[4];
    const float* flnb = (const float*)d_in[5];
    const float* fw2  = (const float*)d_in[6];
    const float* fb2  = (const float*)d_in[7];
    const float* fw3  = (const float*)d_in[8];
    const float* fb3  = (const float*)d_in[9];
    const float* cw1  = (const float*)d_in[10];
    const float* cb1  = (const float*)d_in[11];
    const float* cw2  = (const float*)d_in[12];
    const float* cb2  = (const float*)d_in[13];
    const float* sw1  = (const float*)d_in[14];
    const float* sb1  = (const float*)d_in[15];
    const float* slng = (const float*)d_in[16];
    const float* slnb = (const float*)d_in[17];
    const float* sw2  = (const float*)d_in[18];
    const float* sb2  = (const float*)d_in[19];
    const float* sw3  = (const float*)d_in[20];
    const float* sb3  = (const float*)d_in[21];
    const float* gcp  = (const float*)d_in[22];

    float* out    = (float*)d_out;
    float* desync = out;                    // 8192
    float* order  = out + 8192;             // 1
    float* phases = out + 8193;             // 8192
    float* freqo  = out + 16385;            // 8192
    float* coupo  = out + 24577;            // 8192
    float* synco  = out + 32769;            // 8192*260
    float* coh    = out + 2162689;          // 1

    char* wsb = (char*)d_ws;
    float*    cs  = (float*)(wsb + 0);           // 32 KB
    unsigned* vAu = (unsigned*)(wsb + 32768);    // 32 KB (half2/row)
    unsigned* vBu = (unsigned*)(wsb + 65536);    // 32 KB
    float* pcAf = (float*)(wsb + 98304);         // fp32 fallback buffers
    float* psAf = (float*)(wsb + 131072);
    float* pcBf = (float*)(wsb + 163840);
    float* psBf = (float*)(wsb + 196608);
    unsigned char* Ap = (unsigned char*)(wsb + 262144);  // 72 MiB packed A

    const bool usepack = ws_size >= (size_t)262144 + (size_t)NN * ROWB;

    if (usepack) {
        convert_pack_kernel<<<NN, 512, 0, stream>>>(A, Ap);
    }
    pre_kernel<<<NN / RPB, 256, 0, stream>>>(x, fw1, fb1, flng, flnb, fw2, fb2, fw3, fb3,
                                             cw1, cb1, cw2, cb2, gcp,
                                             freqo, coupo, cs, phases, pcAf, psAf, vAu);
    if (usepack) {
        for (int t = 0; t < 60; ++t) {
            const unsigned* vin = (t & 1) ? vBu : vAu;
            unsigned* vout = (t & 1) ? vAu : vBu;
            step_kernel_p<<<NN / SROWS, 512, 0, stream>>>(Ap, vin, freqo, cs, phases, vout);
        }
    } else {
        for (int t = 0; t < 60; ++t) {
            const float* pin  = (t & 1) ? pcBf : pcAf;
            const float* sin_ = (t & 1) ? psBf : psAf;
            float* pout = (t & 1) ? pcAf : pcBf;
            float* sout = (t & 1) ? psAf : psBf;
            step_kernel<<<NN / FSROWS, 256, 0, stream>>>(A, pin, sin_, freqo, cs, phases, pout, sout);
        }
    }
    post_kernel<<<NN / RPB, 256, 0, stream>>>(x, phases, sw1, sb1, slng, slnb, sw2, sb2, sw3, sb3,
                                              synco, desync);
    reduce_kernel<<<1, 1024, 0, stream>>>(phases, order, coh);
}